// Round 2
// 3741.371 us; speedup vs baseline: 1.2938x; 1.2938x over previous
//
#include <hip/hip_runtime.h>
#include <cmath>

// ---------------------------------------------------------------------------
// RegRNN: out[b,t,:] = h_t ; h_t = tanh(xproj[b,t,:] + h_{t-1} @ Whh^T)
// xproj = seq @ Wih^T + bias   (Wih/Whh hard-concrete gated, fp16)
//
// Phase A: MFMA fp16 GEMM writes xproj straight into d_out (in-place reuse).
// Phase B: persistent kernel, 32 WGs = 4 batch-groups x 8 j-slices (128 cols).
//          Whh slice (128 cols x 1024) in 256 VGPRs/thread.
//          h exchanged via RELAXED AGENT-scope atomics in a FRAGMENT-READY
//          layout F[c][lane][8]: every agent load/store is 64-lane contiguous
//          (1KB burst per wave instruction, no gather). One chunk = 64 lanes
//          x 16B = 1024B = 128 u64 (consumer stride MUST match producer's).
//          Per-WG completion flags (no central RMW): flag[jw]=t+1 stored
//          after __syncthreads' implicit vmcnt(0) drain; consumers poll min
//          of 8 flags. Parity double-buffer WAR-safe by flag monotonicity.
// ---------------------------------------------------------------------------

typedef _Float16 v8h __attribute__((ext_vector_type(8)));
typedef float    v4f __attribute__((ext_vector_type(4)));
typedef unsigned long long u64;

#define BB 64
#define TT 512
#define HH 1024
#define OUT_MAIN (BB * TT * HH) // 33554432
// ws layout (bytes)
#define OFF_WIH  0u
#define OFF_WHH  (2u << 20)
#define OFF_BIAS (4u << 20)
#define OFF_HBUF ((4u << 20) + 8192u)          // 2 parities * 4 groups * 16384 halves
#define OFF_FLG  ((4u << 20) + 8192u + 262144u)

#define ALD(p)    __hip_atomic_load((p),        __ATOMIC_RELAXED, __HIP_MEMORY_SCOPE_AGENT)
#define AST(p, v) __hip_atomic_store((p), (v),  __ATOMIC_RELAXED, __HIP_MEMORY_SCOPE_AGENT)

__device__ __forceinline__ float hc_gate(float x) {
    float s = 1.0f / (1.0f + __expf(-x));
    float g = s * 1.2f - 0.1f;              // sigmoid*(LB-LA)+LA
    return fminf(1.0f, fmaxf(0.0f, g));
}

__device__ __forceinline__ float fast_tanh(float x) {
    // tanh(x) = 1 - 2/(e^{2x}+1); exp->inf and ->0 both saturate correctly.
    float e = __expf(2.0f * x);
    return 1.0f - 2.0f * __builtin_amdgcn_rcpf(e + 1.0f);
}

// ---------------- prep: gate+cast weights, bias, zero h buffers ------------
__global__ void prep_kernel(const float* __restrict__ w_ih, const float* __restrict__ w_ih_mask,
                            const float* __restrict__ w_hh, const float* __restrict__ w_hh_mask,
                            const float* __restrict__ b_ih, const float* __restrict__ b_ih_mask,
                            const float* __restrict__ b_hh, const float* __restrict__ b_hh_mask,
                            _Float16* __restrict__ Wih, _Float16* __restrict__ Whh,
                            float* __restrict__ bias, _Float16* __restrict__ hbuf,
                            int* __restrict__ flg) {
    const int idx = blockIdx.x * 256 + threadIdx.x;   // grid 4096*256 = 1048576 exact
    Wih[idx] = (_Float16)(hc_gate(w_ih_mask[idx]) * w_ih[idx]);
    Whh[idx] = (_Float16)(hc_gate(w_hh_mask[idx]) * w_hh[idx]);
    if (idx < HH)
        bias[idx] = hc_gate(b_ih_mask[idx]) * b_ih[idx] + hc_gate(b_hh_mask[idx]) * b_hh[idx];
    if (idx < 131072) hbuf[idx] = (_Float16)0.0f;     // both parities zeroed (h0 = 0)
    if (idx < 32) flg[idx] = 0;
}

// ---------------- Phase A: xproj GEMM --------------------------------------
// C[m,n] = sum_k seq[m,k]*Wih[n,k] + bias[n], 128x128 tile, BK=32, 256 thr.
__global__ __launch_bounds__(256, 2) void gemm_xproj(const float* __restrict__ seq,
                                                     const _Float16* __restrict__ Wih,
                                                     const float* __restrict__ bias,
                                                     float* __restrict__ out) {
    __shared__ _Float16 As[128][40];   // +8 pad: row stride 80B = 20 banks -> 2-way (free)
    __shared__ _Float16 Bs[128][40];

    const int tid  = threadIdx.x;
    const int lane = tid & 63;
    const int w    = tid >> 6;
    const int bid  = blockIdx.x;
    const int m0 = (bid >> 3) * 128;
    const int n0 = (bid & 7) * 128;
    const int mw = (w >> 1) * 64, nw = (w & 1) * 64;

    const int sr = tid >> 1;            // staging row 0..127
    const int sc = (tid & 1) * 16;      // staging col 0/16

    const float*    aSrc = seq + (m0 + sr) * HH + sc;
    const _Float16* bSrc = Wih + (n0 + sr) * HH + sc;

    const v4f vzero = {0.f, 0.f, 0.f, 0.f};
    v4f acc[4][4];
#pragma unroll
    for (int i = 0; i < 4; i++)
#pragma unroll
        for (int j = 0; j < 4; j++) acc[i][j] = vzero;

    const int arow = mw + (lane & 15);
    const int brow = nw + (lane & 15);
    const int kq   = (lane >> 4) * 8;

    for (int k0 = 0; k0 < HH; k0 += 32) {
        // stage A (fp32 -> fp16) and B
        float4 f0 = *(const float4*)(aSrc + 0);
        float4 f1 = *(const float4*)(aSrc + 4);
        float4 f2 = *(const float4*)(aSrc + 8);
        float4 f3 = *(const float4*)(aSrc + 12);
        v8h a0 = {(_Float16)f0.x, (_Float16)f0.y, (_Float16)f0.z, (_Float16)f0.w,
                  (_Float16)f1.x, (_Float16)f1.y, (_Float16)f1.z, (_Float16)f1.w};
        v8h a1 = {(_Float16)f2.x, (_Float16)f2.y, (_Float16)f2.z, (_Float16)f2.w,
                  (_Float16)f3.x, (_Float16)f3.y, (_Float16)f3.z, (_Float16)f3.w};
        v8h b0 = *(const v8h*)(bSrc + 0);
        v8h b1 = *(const v8h*)(bSrc + 8);
        *(v8h*)&As[sr][sc]     = a0;
        *(v8h*)&As[sr][sc + 8] = a1;
        *(v8h*)&Bs[sr][sc]     = b0;
        *(v8h*)&Bs[sr][sc + 8] = b1;
        __syncthreads();

        v8h af[4], bf[4];
#pragma unroll
        for (int mi = 0; mi < 4; mi++) af[mi] = *(const v8h*)&As[mi * 16 + arow][kq];
#pragma unroll
        for (int ni = 0; ni < 4; ni++) bf[ni] = *(const v8h*)&Bs[ni * 16 + brow][kq];
#pragma unroll
        for (int mi = 0; mi < 4; mi++)
#pragma unroll
            for (int ni = 0; ni < 4; ni++)
                acc[mi][ni] = __builtin_amdgcn_mfma_f32_16x16x32_f16(af[mi], bf[ni], acc[mi][ni], 0, 0, 0);
        __syncthreads();
        aSrc += 32;
        bSrc += 32;
    }

    // epilogue: D col = lane&15 (n), row = (lane>>4)*4 + reg (m)  [m89 layout]
    const int colb = lane & 15;
    const int rowq = (lane >> 4) * 4;
#pragma unroll
    for (int ni = 0; ni < 4; ni++) {
        const int col = n0 + nw + ni * 16 + colb;
        const float bz = bias[col];
#pragma unroll
        for (int mi = 0; mi < 4; mi++) {
            const int row = m0 + mw + mi * 16 + rowq;
#pragma unroll
            for (int r = 0; r < 4; r++)
                out[(row + r) * HH + col] = acc[mi][ni][r] + bz;
        }
    }
}

// ---------------- Phase B: persistent recurrence ---------------------------
// 32 WGs: g = bid>>3 (batch group of 16), jw = bid&7 (128 output cols).
// Whh slice: Wf[64] v8h = 256 VGPRs/thread (2 col-fragments x 32 k-chunks).
// hbuf layout: F[parity][g][c][lane][e] = h[lane&15][c*32 + (lane>>4)*8 + e]
//   chunk c = 1024B = 128 u64, lane-contiguous; agent ops fully coalesced.
__global__ __launch_bounds__(256, 1) void rnn_steps(const _Float16* __restrict__ Whh,
                                                    float* __restrict__ out,
                                                    _Float16* __restrict__ hbuf,
                                                    int* __restrict__ flg) {
    __shared__ _Float16 tile[16 * 128];   // 4 KB, XOR-swizzled on 16B groups

    const int tid  = threadIdx.x;
    const int lane = tid & 63;
    const int w    = tid >> 6;
    const int bid  = blockIdx.x;
    const int g    = bid >> 3;
    const int jw   = bid & 7;

    const int l15 = lane & 15;
    const int kq  = (lane >> 4) * 8;      // k sub-offset of this lane's fragment
    const int bq  = (lane >> 4) * 4;      // D row base = local batch index

    const int col0 = jw * 128 + w * 32 + l15;   // ni=0 output column (== B row n)

    // Whh fragments: Wf[c*2+ni] = Whh[(col0+16*ni)*1024 + c*32 + kq .. +8]
    v8h Wf[64];
    {
        const _Float16* w0 = Whh + col0 * 1024 + kq;
        const _Float16* w1 = Whh + (col0 + 16) * 1024 + kq;
#pragma unroll
        for (int c = 0; c < 32; c++) {
            Wf[c * 2 + 0] = *(const v8h*)(w0 + c * 32);
            Wf[c * 2 + 1] = *(const v8h*)(w1 + c * 32);
        }
    }

    // xproj prefetch for t=0 (gemm output staged in d_out)
    float xp[2][4];
#pragma unroll
    for (int r = 0; r < 4; r++) {
        const float* xs = out + ((g * 16 + bq + r) * TT + 0) * HH + col0;
        xp[0][r] = xs[0];
        xp[1][r] = xs[16];
    }

    int* fg = flg + g * 8;

    for (int t = 0; t < TT; t++) {
        if (tid == 0) {
            for (;;) {
                int m = ALD(fg + 0);
#pragma unroll
                for (int i = 1; i < 8; i++) {
                    int v = ALD(fg + i);
                    m = v < m ? v : m;
                }
                if (m >= t) break;
                __builtin_amdgcn_s_sleep(1);
            }
        }
        __syncthreads();   // A: release all waves into step t

        // h_{t-1} fragment loads: fully lane-contiguous agent 8B atomics.
        // chunk c at u64 offset c*128; this lane's slot at +lane*2.
        const u64* pc = (const u64*)(hbuf + ((t & 1) * 4 + g) * 16384) + lane * 2;
        v4f aA0 = {0.f, 0.f, 0.f, 0.f}, aA1 = aA0, aB0 = aA0, aB1 = aA0;
#pragma unroll
        for (int cc = 0; cc < 8; cc++) {
            union { v8h v; u64 u[2]; } h0, h1, h2, h3;
            const u64* p = pc + cc * 512;             // 4 chunks * 128 u64
            h0.u[0] = ALD(p);        h0.u[1] = ALD(p + 1);
            h1.u[0] = ALD(p + 128);  h1.u[1] = ALD(p + 129);
            h2.u[0] = ALD(p + 256);  h2.u[1] = ALD(p + 257);
            h3.u[0] = ALD(p + 384);  h3.u[1] = ALD(p + 385);
            aA0 = __builtin_amdgcn_mfma_f32_16x16x32_f16(h0.v, Wf[(cc * 4 + 0) * 2 + 0], aA0, 0, 0, 0);
            aA1 = __builtin_amdgcn_mfma_f32_16x16x32_f16(h0.v, Wf[(cc * 4 + 0) * 2 + 1], aA1, 0, 0, 0);
            aB0 = __builtin_amdgcn_mfma_f32_16x16x32_f16(h1.v, Wf[(cc * 4 + 1) * 2 + 0], aB0, 0, 0, 0);
            aB1 = __builtin_amdgcn_mfma_f32_16x16x32_f16(h1.v, Wf[(cc * 4 + 1) * 2 + 1], aB1, 0, 0, 0);
            aA0 = __builtin_amdgcn_mfma_f32_16x16x32_f16(h2.v, Wf[(cc * 4 + 2) * 2 + 0], aA0, 0, 0, 0);
            aA1 = __builtin_amdgcn_mfma_f32_16x16x32_f16(h2.v, Wf[(cc * 4 + 2) * 2 + 1], aA1, 0, 0, 0);
            aB0 = __builtin_amdgcn_mfma_f32_16x16x32_f16(h3.v, Wf[(cc * 4 + 3) * 2 + 0], aB0, 0, 0, 0);
            aB1 = __builtin_amdgcn_mfma_f32_16x16x32_f16(h3.v, Wf[(cc * 4 + 3) * 2 + 1], aB1, 0, 0, 0);
        }
        const v4f av0 = aA0 + aB0;
        const v4f av1 = aA1 + aB1;

        // tanh + LDS transpose into fragment-ready order (XOR-swizzled rows)
        float hv[2][4];
#pragma unroll
        for (int r = 0; r < 4; r++) {
            hv[0][r] = fast_tanh(xp[0][r] + av0[r]);
            hv[1][r] = fast_tanh(xp[1][r] + av1[r]);
            const int row = bq + r;
            const int sw  = (row & 7) << 4;
            char* base = (char*)tile + row * 256;
            *(_Float16*)(base + (((w * 32 + l15) * 2) ^ sw))      = (_Float16)hv[0][r];
            *(_Float16*)(base + (((w * 32 + 16 + l15) * 2) ^ sw)) = (_Float16)hv[1][r];
        }
        __syncthreads();   // B: transpose tile complete

        // store 4 chunks (jw*4 .. jw*4+3), each 1KB lane-contiguous:
        // thread t: chunk jw*4 + (tid>>6), dest lane-slot l = tid&63.
        {
            const int cpr = tid >> 6;
            const int l   = tid & 63;
            const int row = l & 15;
            const int cb  = (cpr * 32 + (l >> 4) * 8) * 2;   // byte col offset in tile row
            union { v8h v; u64 u[2]; } uu;
            uu.v = *(const v8h*)((const char*)tile + row * 256 + (cb ^ ((row & 7) << 4)));
            u64* dst = (u64*)(hbuf + (((t + 1) & 1) * 4 + g) * 16384 + (jw * 4 + cpr) * 512) + l * 2;
            AST(dst,     uu.u[0]);
            AST(dst + 1, uu.u[1]);
        }
        __syncthreads();   // C: implicit vmcnt(0) -> all waves' h-stores drained

        if (tid == 0) AST(&fg[jw], t + 1);

        // off critical path: fp32 outputs + next xproj prefetch (hide under poll)
#pragma unroll
        for (int r = 0; r < 4; r++) {
            const int bg = g * 16 + bq + r;
            float* o = out + (bg * TT + t) * HH + col0;
            o[0]  = hv[0][r];
            o[16] = hv[1][r];
            if (t == TT - 1) {
                float* o2 = out + OUT_MAIN + bg * HH + col0;
                o2[0]  = hv[0][r];
                o2[16] = hv[1][r];
            }
        }
        if (t + 1 < TT) {
#pragma unroll
            for (int r = 0; r < 4; r++) {
                const float* xs = out + ((g * 16 + bq + r) * TT + (t + 1)) * HH + col0;
                xp[0][r] = xs[0];
                xp[1][r] = xs[16];
            }
        }
    }
}

// ---------------------------------------------------------------------------
extern "C" void kernel_launch(void* const* d_in, const int* in_sizes, int n_in,
                              void* d_out, int out_size, void* d_ws, size_t ws_size,
                              hipStream_t stream) {
    const float* seq       = (const float*)d_in[0];
    const float* w_ih      = (const float*)d_in[1];
    const float* w_ih_mask = (const float*)d_in[2];
    const float* w_hh      = (const float*)d_in[3];
    const float* w_hh_mask = (const float*)d_in[4];
    const float* b_ih      = (const float*)d_in[5];
    const float* b_ih_mask = (const float*)d_in[6];
    const float* b_hh      = (const float*)d_in[7];
    const float* b_hh_mask = (const float*)d_in[8];

    float* out = (float*)d_out;
    char*  ws  = (char*)d_ws;
    _Float16* Wih  = (_Float16*)(ws + OFF_WIH);
    _Float16* Whh  = (_Float16*)(ws + OFF_WHH);
    float*    bias = (float*)(ws + OFF_BIAS);
    _Float16* hbuf = (_Float16*)(ws + OFF_HBUF);
    int*      flg  = (int*)(ws + OFF_FLG);

    prep_kernel<<<dim3(4096), dim3(256), 0, stream>>>(w_ih, w_ih_mask, w_hh, w_hh_mask,
                                                      b_ih, b_ih_mask, b_hh, b_hh_mask,
                                                      Wih, Whh, bias, hbuf, flg);
    gemm_xproj<<<dim3(2048), dim3(256), 0, stream>>>(seq, Wih, bias, out);
    rnn_steps<<<dim3(32), dim3(256), 0, stream>>>(Whh, out, hbuf, flg);
}

// Round 5
// 2403.874 us; speedup vs baseline: 2.0137x; 1.5564x over previous
//
#include <hip/hip_runtime.h>
#include <cmath>

// ---------------------------------------------------------------------------
// RegRNN: out[b,t,:] = h_t ; h_t = tanh(xproj[b,t,:] + h_{t-1} @ Whh^T)
// xproj = seq @ Wih^T + bias   (Wih/Whh hard-concrete gated, fp16)
//
// Phase A: MFMA fp16 GEMM writes xproj straight into d_out (in-place reuse).
// Phase B: persistent kernel, 32 WGs = 4 batch-groups x 8 j-slices (128 cols).
//          Whh slice (128 cols x 1024) register-resident.
//          Sync skeleton = round-2-proven: tid0 polls all 8 group flags
//          (s_sleep backoff) then __syncthreads releases the WG.
//          Traffic path = cooperative: after release, chunk i*4+w (slice i)
//          is loaded by wave w only -> LDS hlds (28KB/WG/step vs 128KB when
//          every wave loads everything); own slice short-circuited from the
//          producer epilogue (never round-trips L3). MFMA reads hlds.
//          Flags: flag[jw]=t+1 stored after __syncthreads' implicit vmcnt(0)
//          drain. WAR-safe: all 8 flags >= t observed before the release
//          barrier; producer stores to parity (t+1)&1 happen after the
//          post-MFMA barriers, hence after every group WG finished step t-1
//          (incl. its reads of parity (t+1)&1). Parity double-buffer.
// ---------------------------------------------------------------------------

typedef _Float16 v8h __attribute__((ext_vector_type(8)));
typedef float    v4f __attribute__((ext_vector_type(4)));
typedef unsigned long long u64;

#define BB 64
#define TT 512
#define HH 1024
#define OUT_MAIN (BB * TT * HH) // 33554432
// ws layout (bytes)
#define OFF_WIH  0u
#define OFF_WHH  (2u << 20)
#define OFF_BIAS (4u << 20)
#define OFF_HBUF ((4u << 20) + 8192u)          // 2 parities * 4 groups * 16384 halves
#define OFF_FLG  ((4u << 20) + 8192u + 262144u)

#define ALD(p)    __hip_atomic_load((p),        __ATOMIC_RELAXED, __HIP_MEMORY_SCOPE_AGENT)
#define AST(p, v) __hip_atomic_store((p), (v),  __ATOMIC_RELAXED, __HIP_MEMORY_SCOPE_AGENT)

__device__ __forceinline__ float hc_gate(float x) {
    float s = 1.0f / (1.0f + __expf(-x));
    float g = s * 1.2f - 0.1f;              // sigmoid*(LB-LA)+LA
    return fminf(1.0f, fmaxf(0.0f, g));
}

__device__ __forceinline__ float fast_tanh(float x) {
    // tanh(x) = 1 - 2/(e^{2x}+1); exp->inf and ->0 both saturate correctly.
    float e = __expf(2.0f * x);
    return 1.0f - 2.0f * __builtin_amdgcn_rcpf(e + 1.0f);
}

// ---------------- prep: gate+cast weights, bias, zero h buffers ------------
__global__ void prep_kernel(const float* __restrict__ w_ih, const float* __restrict__ w_ih_mask,
                            const float* __restrict__ w_hh, const float* __restrict__ w_hh_mask,
                            const float* __restrict__ b_ih, const float* __restrict__ b_ih_mask,
                            const float* __restrict__ b_hh, const float* __restrict__ b_hh_mask,
                            _Float16* __restrict__ Wih, _Float16* __restrict__ Whh,
                            float* __restrict__ bias, _Float16* __restrict__ hbuf,
                            int* __restrict__ flg) {
    const int idx = blockIdx.x * 256 + threadIdx.x;   // grid 4096*256 = 1048576 exact
    Wih[idx] = (_Float16)(hc_gate(w_ih_mask[idx]) * w_ih[idx]);
    Whh[idx] = (_Float16)(hc_gate(w_hh_mask[idx]) * w_hh[idx]);
    if (idx < HH)
        bias[idx] = hc_gate(b_ih_mask[idx]) * b_ih[idx] + hc_gate(b_hh_mask[idx]) * b_hh[idx];
    if (idx < 131072) hbuf[idx] = (_Float16)0.0f;     // both parities zeroed (h0 = 0)
    if (idx < 32) flg[idx] = 0;
}

// ---------------- Phase A: xproj GEMM --------------------------------------
// C[m,n] = sum_k seq[m,k]*Wih[n,k] + bias[n], 128x128 tile, BK=32, 256 thr.
__global__ __launch_bounds__(256, 2) void gemm_xproj(const float* __restrict__ seq,
                                                     const _Float16* __restrict__ Wih,
                                                     const float* __restrict__ bias,
                                                     float* __restrict__ out) {
    __shared__ _Float16 As[128][40];   // +8 pad: row stride 80B = 20 banks -> 2-way (free)
    __shared__ _Float16 Bs[128][40];

    const int tid  = threadIdx.x;
    const int lane = tid & 63;
    const int w    = tid >> 6;
    const int bid  = blockIdx.x;
    const int m0 = (bid >> 3) * 128;
    const int n0 = (bid & 7) * 128;
    const int mw = (w >> 1) * 64, nw = (w & 1) * 64;

    const int sr = tid >> 1;            // staging row 0..127
    const int sc = (tid & 1) * 16;      // staging col 0/16

    const float*    aSrc = seq + (m0 + sr) * HH + sc;
    const _Float16* bSrc = Wih + (n0 + sr) * HH + sc;

    const v4f vzero = {0.f, 0.f, 0.f, 0.f};
    v4f acc[4][4];
#pragma unroll
    for (int i = 0; i < 4; i++)
#pragma unroll
        for (int j = 0; j < 4; j++) acc[i][j] = vzero;

    const int arow = mw + (lane & 15);
    const int brow = nw + (lane & 15);
    const int kq   = (lane >> 4) * 8;

    for (int k0 = 0; k0 < HH; k0 += 32) {
        // stage A (fp32 -> fp16) and B
        float4 f0 = *(const float4*)(aSrc + 0);
        float4 f1 = *(const float4*)(aSrc + 4);
        float4 f2 = *(const float4*)(aSrc + 8);
        float4 f3 = *(const float4*)(aSrc + 12);
        v8h a0 = {(_Float16)f0.x, (_Float16)f0.y, (_Float16)f0.z, (_Float16)f0.w,
                  (_Float16)f1.x, (_Float16)f1.y, (_Float16)f1.z, (_Float16)f1.w};
        v8h a1 = {(_Float16)f2.x, (_Float16)f2.y, (_Float16)f2.z, (_Float16)f2.w,
                  (_Float16)f3.x, (_Float16)f3.y, (_Float16)f3.z, (_Float16)f3.w};
        v8h b0 = *(const v8h*)(bSrc + 0);
        v8h b1 = *(const v8h*)(bSrc + 8);
        *(v8h*)&As[sr][sc]     = a0;
        *(v8h*)&As[sr][sc + 8] = a1;
        *(v8h*)&Bs[sr][sc]     = b0;
        *(v8h*)&Bs[sr][sc + 8] = b1;
        __syncthreads();

        v8h af[4], bf[4];
#pragma unroll
        for (int mi = 0; mi < 4; mi++) af[mi] = *(const v8h*)&As[mi * 16 + arow][kq];
#pragma unroll
        for (int ni = 0; ni < 4; ni++) bf[ni] = *(const v8h*)&Bs[ni * 16 + brow][kq];
#pragma unroll
        for (int mi = 0; mi < 4; mi++)
#pragma unroll
            for (int ni = 0; ni < 4; ni++)
                acc[mi][ni] = __builtin_amdgcn_mfma_f32_16x16x32_f16(af[mi], bf[ni], acc[mi][ni], 0, 0, 0);
        __syncthreads();
        aSrc += 32;
        bSrc += 32;
    }

    // epilogue: D col = lane&15 (n), row = (lane>>4)*4 + reg (m)  [m89 layout]
    const int colb = lane & 15;
    const int rowq = (lane >> 4) * 4;
#pragma unroll
    for (int ni = 0; ni < 4; ni++) {
        const int col = n0 + nw + ni * 16 + colb;
        const float bz = bias[col];
#pragma unroll
        for (int mi = 0; mi < 4; mi++) {
            const int row = m0 + mw + mi * 16 + rowq;
#pragma unroll
            for (int r = 0; r < 4; r++)
                out[(row + r) * HH + col] = acc[mi][ni][r] + bz;
        }
    }
}

// ---------------- Phase B: persistent recurrence ---------------------------
// 32 WGs: g = bid>>3 (batch group of 16), jw = bid&7 (128 output cols).
// Whh slice: Wf[64] v8h = 256 regs/thread (2 col-fragments x 32 k-chunks).
// hbuf layout: F[parity][g][c][lane][e] = h[lane&15][c*32 + (lane>>4)*8 + e]
//   chunk c = 1024B = 128 u64, lane-contiguous; agent ops fully coalesced.
//   chunk c belongs to slice c>>2; slice i = chunks i*4..i*4+3.
// hlds (LDS, 32KB) mirrors one (parity,g) region; chunk i*4+w fetched by
//   wave w (slice jw short-circuited from the producer epilogue).
__global__ __launch_bounds__(256, 1) void rnn_steps(const _Float16* __restrict__ Whh,
                                                    float* __restrict__ out,
                                                    _Float16* __restrict__ hbuf,
                                                    int* __restrict__ flg) {
    __shared__ _Float16 tile[16 * 128];          // 4 KB, XOR-swizzled transpose buffer
    __shared__ __align__(16) u64 hlds[32 * 128]; // 32 KB fragment-ready h

    const int tid  = threadIdx.x;
    const int lane = tid & 63;
    const int w    = tid >> 6;
    const int bid  = blockIdx.x;
    const int g    = bid >> 3;
    const int jw   = bid & 7;

    const int l15 = lane & 15;
    const int kq  = (lane >> 4) * 8;      // k sub-offset of this lane's fragment
    const int bq  = (lane >> 4) * 4;      // D row base = local batch index

    const int col0 = jw * 128 + w * 32 + l15;   // ni=0 output column (== B row n)

    // Whh fragments: Wf[c*2+ni] = Whh[(col0+16*ni)*1024 + c*32 + kq .. +8]
    v8h Wf[64];
    {
        const _Float16* w0 = Whh + col0 * 1024 + kq;
        const _Float16* w1 = Whh + (col0 + 16) * 1024 + kq;
#pragma unroll
        for (int c = 0; c < 32; c++) {
            Wf[c * 2 + 0] = *(const v8h*)(w0 + c * 32);
            Wf[c * 2 + 1] = *(const v8h*)(w1 + c * 32);
        }
    }

    // own-slice hlds init (h0 = 0); other 28 chunks loaded from hbuf (zeroed).
    {
        u64* q = &hlds[(jw * 4 + w) * 128 + lane * 2];
        q[0] = 0ull; q[1] = 0ull;
    }
    // (first loop iteration's release barrier orders this vs. reads)

    // xproj prefetch for t=0 (gemm output staged in d_out)
    float xp[2][4];
#pragma unroll
    for (int r = 0; r < 4; r++) {
        const float* xs = out + ((g * 16 + bq + r) * TT + 0) * HH + col0;
        xp[0][r] = xs[0];
        xp[1][r] = xs[16];
    }

    int* fg = flg + g * 8;

    for (int t = 0; t < TT; t++) {
        // ---- tid0 polls all 8 group flags (round-2-proven skeleton)
        if (tid == 0) {
            for (;;) {
                int m = ALD(fg + 0);
#pragma unroll
                for (int i = 1; i < 8; i++) {
                    int v = ALD(fg + i);
                    m = v < m ? v : m;
                }
                if (m >= t) break;
                __builtin_amdgcn_s_sleep(1);
            }
        }
        __syncthreads();   // A: release all waves into step t (flags all >= t)

        // ---- cooperative fetch: wave w loads chunk i*4+w of each peer slice i
        {
            const u64* hbp = (const u64*)(hbuf + ((t & 1) * 4 + g) * 16384);
            u64 dv[16];
#pragma unroll
            for (int i = 0; i < 8; i++) {
                if (i != jw) {
                    const u64* p = hbp + (i * 4 + w) * 128 + lane * 2;
                    dv[2 * i]     = ALD(p);
                    dv[2 * i + 1] = ALD(p + 1);
                }
            }
#pragma unroll
            for (int i = 0; i < 8; i++) {
                if (i != jw) {
                    u64* q = &hlds[(i * 4 + w) * 128 + lane * 2];
                    q[0] = dv[2 * i];
                    q[1] = dv[2 * i + 1];
                }
            }
        }
        __syncthreads();   // D: full h_{t-1} staged in hlds

        // ---- MFMA over 32 chunks from LDS (contiguous 16B reads, conflict-free)
        v4f aA0 = {0.f, 0.f, 0.f, 0.f}, aA1 = aA0, aB0 = aA0, aB1 = aA0;
#pragma unroll
        for (int cc = 0; cc < 8; cc++) {
            const u64* q = &hlds[cc * 512 + lane * 2];
            v8h h0 = *(const v8h*)(q);
            v8h h1 = *(const v8h*)(q + 128);
            v8h h2 = *(const v8h*)(q + 256);
            v8h h3 = *(const v8h*)(q + 384);
            aA0 = __builtin_amdgcn_mfma_f32_16x16x32_f16(h0, Wf[(cc * 4 + 0) * 2 + 0], aA0, 0, 0, 0);
            aA1 = __builtin_amdgcn_mfma_f32_16x16x32_f16(h0, Wf[(cc * 4 + 0) * 2 + 1], aA1, 0, 0, 0);
            aB0 = __builtin_amdgcn_mfma_f32_16x16x32_f16(h1, Wf[(cc * 4 + 1) * 2 + 0], aB0, 0, 0, 0);
            aB1 = __builtin_amdgcn_mfma_f32_16x16x32_f16(h1, Wf[(cc * 4 + 1) * 2 + 1], aB1, 0, 0, 0);
            aA0 = __builtin_amdgcn_mfma_f32_16x16x32_f16(h2, Wf[(cc * 4 + 2) * 2 + 0], aA0, 0, 0, 0);
            aA1 = __builtin_amdgcn_mfma_f32_16x16x32_f16(h2, Wf[(cc * 4 + 2) * 2 + 1], aA1, 0, 0, 0);
            aB0 = __builtin_amdgcn_mfma_f32_16x16x32_f16(h3, Wf[(cc * 4 + 3) * 2 + 0], aB0, 0, 0, 0);
            aB1 = __builtin_amdgcn_mfma_f32_16x16x32_f16(h3, Wf[(cc * 4 + 3) * 2 + 1], aB1, 0, 0, 0);
        }
        const v4f av0 = aA0 + aB0;
        const v4f av1 = aA1 + aB1;

        // ---- tanh + LDS transpose into fragment-ready order (XOR-swizzled)
        float hv[2][4];
#pragma unroll
        for (int r = 0; r < 4; r++) {
            hv[0][r] = fast_tanh(xp[0][r] + av0[r]);
            hv[1][r] = fast_tanh(xp[1][r] + av1[r]);
            const int row = bq + r;
            const int sw  = (row & 7) << 4;
            char* base = (char*)tile + row * 256;
            *(_Float16*)(base + (((w * 32 + l15) * 2) ^ sw))      = (_Float16)hv[0][r];
            *(_Float16*)(base + (((w * 32 + 16 + l15) * 2) ^ sw)) = (_Float16)hv[1][r];
        }
        __syncthreads();   // B: transpose tile complete

        // ---- producer: own 4 chunks -> global (peers) + hlds (self, t+1)
        {
            const int cpr = tid >> 6;
            const int l   = tid & 63;
            const int row = l & 15;
            const int cb  = (cpr * 32 + (l >> 4) * 8) * 2;   // byte col offset in tile row
            union { v8h v; u64 u[2]; } uu;
            uu.v = *(const v8h*)((const char*)tile + row * 256 + (cb ^ ((row & 7) << 4)));
            u64* dst = (u64*)(hbuf + (((t + 1) & 1) * 4 + g) * 16384 + (jw * 4 + cpr) * 512) + l * 2;
            AST(dst,     uu.u[0]);
            AST(dst + 1, uu.u[1]);
            u64* q = &hlds[(jw * 4 + cpr) * 128 + l * 2];   // self short-circuit
            q[0] = uu.u[0];
            q[1] = uu.u[1];
        }
        __syncthreads();   // C: implicit vmcnt(0) -> all waves' h-stores drained

        if (tid == 0) AST(&fg[jw], t + 1);

        // off critical path: fp32 outputs + next xproj prefetch (hide under poll)
#pragma unroll
        for (int r = 0; r < 4; r++) {
            const int bg = g * 16 + bq + r;
            float* o = out + (bg * TT + t) * HH + col0;
            o[0]  = hv[0][r];
            o[16] = hv[1][r];
            if (t == TT - 1) {
                float* o2 = out + OUT_MAIN + bg * HH + col0;
                o2[0]  = hv[0][r];
                o2[16] = hv[1][r];
            }
        }
        if (t + 1 < TT) {
#pragma unroll
            for (int r = 0; r < 4; r++) {
                const float* xs = out + ((g * 16 + bq + r) * TT + (t + 1)) * HH + col0;
                xp[0][r] = xs[0];
                xp[1][r] = xs[16];
            }
        }
    }
}

// ---------------------------------------------------------------------------
extern "C" void kernel_launch(void* const* d_in, const int* in_sizes, int n_in,
                              void* d_out, int out_size, void* d_ws, size_t ws_size,
                              hipStream_t stream) {
    const float* seq       = (const float*)d_in[0];
    const float* w_ih      = (const float*)d_in[1];
    const float* w_ih_mask = (const float*)d_in[2];
    const float* w_hh      = (const float*)d_in[3];
    const float* w_hh_mask = (const float*)d_in[4];
    const float* b_ih      = (const float*)d_in[5];
    const float* b_ih_mask = (const float*)d_in[6];
    const float* b_hh      = (const float*)d_in[7];
    const float* b_hh_mask = (const float*)d_in[8];

    float* out = (float*)d_out;
    char*  ws  = (char*)d_ws;
    _Float16* Wih  = (_Float16*)(ws + OFF_WIH);
    _Float16* Whh  = (_Float16*)(ws + OFF_WHH);
    float*    bias = (float*)(ws + OFF_BIAS);
    _Float16* hbuf = (_Float16*)(ws + OFF_HBUF);
    int*      flg  = (int*)(ws + OFF_FLG);

    prep_kernel<<<dim3(4096), dim3(256), 0, stream>>>(w_ih, w_ih_mask, w_hh, w_hh_mask,
                                                      b_ih, b_ih_mask, b_hh, b_hh_mask,
                                                      Wih, Whh, bias, hbuf, flg);
    gemm_xproj<<<dim3(2048), dim3(256), 0, stream>>>(seq, Wih, bias, out);
    rnn_steps<<<dim3(32), dim3(256), 0, stream>>>(Whh, out, hbuf, flg);
}

// Round 7
// 2320.106 us; speedup vs baseline: 2.0864x; 1.0361x over previous
//
#include <hip/hip_runtime.h>
#include <cmath>

// ---------------------------------------------------------------------------
// RegRNN: out[b,t,:] = h_t ; h_t = tanh(xproj[b,t,:] + h_{t-1} @ Whh^T)
// xproj = seq @ Wih^T + bias   (Wih/Whh hard-concrete gated, fp16)
//
// Phase A: MFMA fp16 GEMM writes xproj straight into d_out (in-place reuse).
// Phase B: persistent kernel, 32 WGs = 4 batch-groups x 8 j-slices (128 cols).
//          Whh slice register-resident. h exchange in fragment-ready layout
//          F[c][lane][8] (chunk = 1KB = 512 halves = 128 u64), PER-WAVE:
//            producer wave w: store own chunk jw*4+w (2x8B agent stores) ->
//              s_waitcnt vmcnt(0) (own stores only) -> lane0 stores
//              seqno[parity][g][jw*4+w] = t+1.
//            consumer wave w: lanes 0..7 poll peers' seqno[i*4+w] >= t
//              (__all + s_sleep), load 7 peer chunks -> LDS hlds; own slice
//              short-circuited. Only 2 barriers/step (hlds-ready, tile-done).
//          WAR safety is per-wave exact: X.wave w overwrites only chunk-row w
//          of parity (t+1)&1, read only by peers' wave w at step t-1;
//          seqno[i*4+w] >= t attests peer i's wave w completed step t-1
//          (its vmcnt(0) drained those loads before publishing). Monotone
//          seqnos, parity double-buffer; grounded at t=0 by zeroed seqnos.
//          NOTE chunk strides: halves *512, u64 *128 -- r6 bug was *128 on
//          the _Float16 pointer (256B stride); offsets now applied post-cast.
// ---------------------------------------------------------------------------

typedef _Float16 v8h __attribute__((ext_vector_type(8)));
typedef float    v4f __attribute__((ext_vector_type(4)));
typedef unsigned long long u64;

#define BB 64
#define TT 512
#define HH 1024
#define OUT_MAIN (BB * TT * HH) // 33554432
// ws layout (bytes)
#define OFF_WIH  0u
#define OFF_WHH  (2u << 20)
#define OFF_BIAS (4u << 20)
#define OFF_HBUF ((4u << 20) + 8192u)          // 2 parities * 4 groups * 16384 halves
#define OFF_SEQ  ((4u << 20) + 8192u + 262144u) // 2 par * 4 groups * 32 chunk seqnos

#define ALD(p)    __hip_atomic_load((p),        __ATOMIC_RELAXED, __HIP_MEMORY_SCOPE_AGENT)
#define AST(p, v) __hip_atomic_store((p), (v),  __ATOMIC_RELAXED, __HIP_MEMORY_SCOPE_AGENT)

__device__ __forceinline__ float hc_gate(float x) {
    float s = 1.0f / (1.0f + __expf(-x));
    float g = s * 1.2f - 0.1f;              // sigmoid*(LB-LA)+LA
    return fminf(1.0f, fmaxf(0.0f, g));
}

__device__ __forceinline__ float fast_tanh(float x) {
    // tanh(x) = 1 - 2/(e^{2x}+1); exp->inf and ->0 both saturate correctly.
    float e = __expf(2.0f * x);
    return 1.0f - 2.0f * __builtin_amdgcn_rcpf(e + 1.0f);
}

// ---------------- prep: gate+cast weights, bias, zero h buffers ------------
__global__ void prep_kernel(const float* __restrict__ w_ih, const float* __restrict__ w_ih_mask,
                            const float* __restrict__ w_hh, const float* __restrict__ w_hh_mask,
                            const float* __restrict__ b_ih, const float* __restrict__ b_ih_mask,
                            const float* __restrict__ b_hh, const float* __restrict__ b_hh_mask,
                            _Float16* __restrict__ Wih, _Float16* __restrict__ Whh,
                            float* __restrict__ bias, _Float16* __restrict__ hbuf,
                            int* __restrict__ seqf) {
    const int idx = blockIdx.x * 256 + threadIdx.x;   // grid 4096*256 = 1048576 exact
    Wih[idx] = (_Float16)(hc_gate(w_ih_mask[idx]) * w_ih[idx]);
    Whh[idx] = (_Float16)(hc_gate(w_hh_mask[idx]) * w_hh[idx]);
    if (idx < HH)
        bias[idx] = hc_gate(b_ih_mask[idx]) * b_ih[idx] + hc_gate(b_hh_mask[idx]) * b_hh[idx];
    if (idx < 131072) hbuf[idx] = (_Float16)0.0f;     // both parities zeroed (h0 = 0)
    if (idx < 256) seqf[idx] = 0;                     // all seqnos = 0 (t=0 passes)
}

// ---------------- Phase A: xproj GEMM --------------------------------------
// C[m,n] = sum_k seq[m,k]*Wih[n,k] + bias[n], 128x128 tile, BK=32, 256 thr.
__global__ __launch_bounds__(256, 2) void gemm_xproj(const float* __restrict__ seq,
                                                     const _Float16* __restrict__ Wih,
                                                     const float* __restrict__ bias,
                                                     float* __restrict__ out) {
    __shared__ _Float16 As[128][40];   // +8 pad: row stride 80B = 20 banks -> 2-way (free)
    __shared__ _Float16 Bs[128][40];

    const int tid  = threadIdx.x;
    const int lane = tid & 63;
    const int w    = tid >> 6;
    const int bid  = blockIdx.x;
    const int m0 = (bid >> 3) * 128;
    const int n0 = (bid & 7) * 128;
    const int mw = (w >> 1) * 64, nw = (w & 1) * 64;

    const int sr = tid >> 1;            // staging row 0..127
    const int sc = (tid & 1) * 16;      // staging col 0/16

    const float*    aSrc = seq + (m0 + sr) * HH + sc;
    const _Float16* bSrc = Wih + (n0 + sr) * HH + sc;

    const v4f vzero = {0.f, 0.f, 0.f, 0.f};
    v4f acc[4][4];
#pragma unroll
    for (int i = 0; i < 4; i++)
#pragma unroll
        for (int j = 0; j < 4; j++) acc[i][j] = vzero;

    const int arow = mw + (lane & 15);
    const int brow = nw + (lane & 15);
    const int kq   = (lane >> 4) * 8;

    for (int k0 = 0; k0 < HH; k0 += 32) {
        // stage A (fp32 -> fp16) and B
        float4 f0 = *(const float4*)(aSrc + 0);
        float4 f1 = *(const float4*)(aSrc + 4);
        float4 f2 = *(const float4*)(aSrc + 8);
        float4 f3 = *(const float4*)(aSrc + 12);
        v8h a0 = {(_Float16)f0.x, (_Float16)f0.y, (_Float16)f0.z, (_Float16)f0.w,
                  (_Float16)f1.x, (_Float16)f1.y, (_Float16)f1.z, (_Float16)f1.w};
        v8h a1 = {(_Float16)f2.x, (_Float16)f2.y, (_Float16)f2.z, (_Float16)f2.w,
                  (_Float16)f3.x, (_Float16)f3.y, (_Float16)f3.z, (_Float16)f3.w};
        v8h b0 = *(const v8h*)(bSrc + 0);
        v8h b1 = *(const v8h*)(bSrc + 8);
        *(v8h*)&As[sr][sc]     = a0;
        *(v8h*)&As[sr][sc + 8] = a1;
        *(v8h*)&Bs[sr][sc]     = b0;
        *(v8h*)&Bs[sr][sc + 8] = b1;
        __syncthreads();

        v8h af[4], bf[4];
#pragma unroll
        for (int mi = 0; mi < 4; mi++) af[mi] = *(const v8h*)&As[mi * 16 + arow][kq];
#pragma unroll
        for (int ni = 0; ni < 4; ni++) bf[ni] = *(const v8h*)&Bs[ni * 16 + brow][kq];
#pragma unroll
        for (int mi = 0; mi < 4; mi++)
#pragma unroll
            for (int ni = 0; ni < 4; ni++)
                acc[mi][ni] = __builtin_amdgcn_mfma_f32_16x16x32_f16(af[mi], bf[ni], acc[mi][ni], 0, 0, 0);
        __syncthreads();
        aSrc += 32;
        bSrc += 32;
    }

    // epilogue: D col = lane&15 (n), row = (lane>>4)*4 + reg (m)  [m89 layout]
    const int colb = lane & 15;
    const int rowq = (lane >> 4) * 4;
#pragma unroll
    for (int ni = 0; ni < 4; ni++) {
        const int col = n0 + nw + ni * 16 + colb;
        const float bz = bias[col];
#pragma unroll
        for (int mi = 0; mi < 4; mi++) {
            const int row = m0 + mw + mi * 16 + rowq;
#pragma unroll
            for (int r = 0; r < 4; r++)
                out[(row + r) * HH + col] = acc[mi][ni][r] + bz;
        }
    }
}

// ---------------- Phase B: persistent recurrence ---------------------------
// 32 WGs: g = bid>>3 (batch group of 16), jw = bid&7 (128 output cols).
// Whh slice: Wf[64] v8h = 256 regs/thread (2 col-fragments x 32 k-chunks).
// hbuf layout: F[parity][g][c][lane][e] = h[lane&15][c*32 + (lane>>4)*8 + e]
//   chunk c = 1024B = 128 u64, lane-contiguous; slice i = chunks i*4..i*4+3;
//   chunk-row = c&3 = owning wave. seqno[parity][g][c] guards chunk c.
__global__ __launch_bounds__(256, 1) void rnn_steps(const _Float16* __restrict__ Whh,
                                                    float* __restrict__ out,
                                                    _Float16* __restrict__ hbuf,
                                                    int* __restrict__ seqf) {
    __shared__ _Float16 tile[16 * 128];          // 4 KB, XOR-swizzled transpose buffer
    __shared__ __align__(16) u64 hlds[32 * 128]; // 32 KB fragment-ready h

    const int tid  = threadIdx.x;
    const int lane = tid & 63;
    const int w    = tid >> 6;
    const int bid  = blockIdx.x;
    const int g    = bid >> 3;
    const int jw   = bid & 7;

    const int l15 = lane & 15;
    const int kq  = (lane >> 4) * 8;      // k sub-offset of this lane's fragment
    const int bq  = (lane >> 4) * 4;      // D row base = local batch index

    const int col0 = jw * 128 + w * 32 + l15;   // ni=0 output column (== B row n)

    // Whh fragments: Wf[c*2+ni] = Whh[(col0+16*ni)*1024 + c*32 + kq .. +8]
    v8h Wf[64];
    {
        const _Float16* w0 = Whh + col0 * 1024 + kq;
        const _Float16* w1 = Whh + (col0 + 16) * 1024 + kq;
#pragma unroll
        for (int c = 0; c < 32; c++) {
            Wf[c * 2 + 0] = *(const v8h*)(w0 + c * 32);
            Wf[c * 2 + 1] = *(const v8h*)(w1 + c * 32);
        }
    }

    // own-slice hlds init (h0 = 0); peer chunks loaded from hbuf (zeroed).
    {
        u64* q = &hlds[(jw * 4 + w) * 128 + lane * 2];
        q[0] = 0ull; q[1] = 0ull;
    }
    // (first iteration's barrier D orders this vs. MFMA reads)

    // xproj prefetch for t=0 (gemm output staged in d_out)
    float xp[2][4];
#pragma unroll
    for (int r = 0; r < 4; r++) {
        const float* xs = out + ((g * 16 + bq + r) * TT + 0) * HH + col0;
        xp[0][r] = xs[0];
        xp[1][r] = xs[16];
    }

    // lane l < 8, l != jw polls peer l's chunk-row w seqno
    const int pollIdx = (lane < 8 && lane != jw) ? (lane * 4 + w) : -1;

    for (int t = 0; t < TT; t++) {
        int* sqp = seqf + ((t & 1) * 4 + g) * 32;

        // ---- per-wave poll: 7 peer seqnos observed in parallel by lanes
        for (;;) {
            int ok = 1;
            if (pollIdx >= 0) ok = (ALD(sqp + pollIdx) >= t) ? 1 : 0;
            if (__all(ok)) break;
            __builtin_amdgcn_s_sleep(1);
        }
        asm volatile("" ::: "memory");   // pin: data loads stay after observation

        // ---- load 7 peers' chunk-row w into hlds (own slice short-circuited)
        {
            const u64* hbp = (const u64*)(hbuf + ((t & 1) * 4 + g) * 16384);
            u64 dv[16];
#pragma unroll
            for (int i = 0; i < 8; i++) {
                if (i != jw) {
                    const u64* p = hbp + (i * 4 + w) * 128 + lane * 2;
                    dv[2 * i]     = ALD(p);
                    dv[2 * i + 1] = ALD(p + 1);
                }
            }
#pragma unroll
            for (int i = 0; i < 8; i++) {
                if (i != jw) {
                    u64* q = &hlds[(i * 4 + w) * 128 + lane * 2];
                    q[0] = dv[2 * i];
                    q[1] = dv[2 * i + 1];
                }
            }
        }
        __syncthreads();   // D: full h_{t-1} staged in hlds

        // ---- MFMA over 32 chunks from LDS (contiguous 16B reads, conflict-free)
        v4f aA0 = {0.f, 0.f, 0.f, 0.f}, aA1 = aA0, aB0 = aA0, aB1 = aA0;
#pragma unroll
        for (int cc = 0; cc < 8; cc++) {
            const u64* q = &hlds[cc * 512 + lane * 2];
            v8h h0 = *(const v8h*)(q);
            v8h h1 = *(const v8h*)(q + 128);
            v8h h2 = *(const v8h*)(q + 256);
            v8h h3 = *(const v8h*)(q + 384);
            aA0 = __builtin_amdgcn_mfma_f32_16x16x32_f16(h0, Wf[(cc * 4 + 0) * 2 + 0], aA0, 0, 0, 0);
            aA1 = __builtin_amdgcn_mfma_f32_16x16x32_f16(h0, Wf[(cc * 4 + 0) * 2 + 1], aA1, 0, 0, 0);
            aB0 = __builtin_amdgcn_mfma_f32_16x16x32_f16(h1, Wf[(cc * 4 + 1) * 2 + 0], aB0, 0, 0, 0);
            aB1 = __builtin_amdgcn_mfma_f32_16x16x32_f16(h1, Wf[(cc * 4 + 1) * 2 + 1], aB1, 0, 0, 0);
            aA0 = __builtin_amdgcn_mfma_f32_16x16x32_f16(h2, Wf[(cc * 4 + 2) * 2 + 0], aA0, 0, 0, 0);
            aA1 = __builtin_amdgcn_mfma_f32_16x16x32_f16(h2, Wf[(cc * 4 + 2) * 2 + 1], aA1, 0, 0, 0);
            aB0 = __builtin_amdgcn_mfma_f32_16x16x32_f16(h3, Wf[(cc * 4 + 3) * 2 + 0], aB0, 0, 0, 0);
            aB1 = __builtin_amdgcn_mfma_f32_16x16x32_f16(h3, Wf[(cc * 4 + 3) * 2 + 1], aB1, 0, 0, 0);
        }
        const v4f av0 = aA0 + aB0;
        const v4f av1 = aA1 + aB1;

        // ---- tanh + LDS transpose into fragment-ready order (XOR-swizzled)
        float hv[2][4];
#pragma unroll
        for (int r = 0; r < 4; r++) {
            hv[0][r] = fast_tanh(xp[0][r] + av0[r]);
            hv[1][r] = fast_tanh(xp[1][r] + av1[r]);
            const int row = bq + r;
            const int sw  = (row & 7) << 4;
            char* base = (char*)tile + row * 256;
            *(_Float16*)(base + (((w * 32 + l15) * 2) ^ sw))      = (_Float16)hv[0][r];
            *(_Float16*)(base + (((w * 32 + 16 + l15) * 2) ^ sw)) = (_Float16)hv[1][r];
        }
        __syncthreads();   // B: transpose tile complete (also fences hlds WAR)

        // ---- producer wave w: own chunk jw*4+w -> global + hlds (self, t+1)
        {
            const int row = lane & 15;
            const int cb  = (w * 32 + (lane >> 4) * 8) * 2;   // byte col offset in tile row
            union { v8h v; u64 u[2]; } uu;
            uu.v = *(const v8h*)((const char*)tile + row * 256 + (cb ^ ((row & 7) << 4)));
            // chunk offset applied AFTER the u64 cast: (jw*4+w)*128 u64 = 1024B
            u64* dst = (u64*)(hbuf + (((t + 1) & 1) * 4 + g) * 16384) + (jw * 4 + w) * 128 + lane * 2;
            AST(dst,     uu.u[0]);
            AST(dst + 1, uu.u[1]);
            u64* q = &hlds[(jw * 4 + w) * 128 + lane * 2];   // self short-circuit
            q[0] = uu.u[0];
            q[1] = uu.u[1];
        }
        // drain THIS wave's h-stores to the coherence point, then publish seqno
        asm volatile("s_waitcnt vmcnt(0)" ::: "memory");
        if (lane == 0)
            AST(seqf + (((t + 1) & 1) * 4 + g) * 32 + jw * 4 + w, t + 1);

        // off critical path: fp32 outputs + next xproj prefetch (overlap poll)
#pragma unroll
        for (int r = 0; r < 4; r++) {
            const int bg = g * 16 + bq + r;
            float* o = out + (bg * TT + t) * HH + col0;
            o[0]  = hv[0][r];
            o[16] = hv[1][r];
            if (t == TT - 1) {
                float* o2 = out + OUT_MAIN + bg * HH + col0;
                o2[0]  = hv[0][r];
                o2[16] = hv[1][r];
            }
        }
        if (t + 1 < TT) {
#pragma unroll
            for (int r = 0; r < 4; r++) {
                const float* xs = out + ((g * 16 + bq + r) * TT + (t + 1)) * HH + col0;
                xp[0][r] = xs[0];
                xp[1][r] = xs[16];
            }
        }
    }
}

// ---------------------------------------------------------------------------
extern "C" void kernel_launch(void* const* d_in, const int* in_sizes, int n_in,
                              void* d_out, int out_size, void* d_ws, size_t ws_size,
                              hipStream_t stream) {
    const float* seq       = (const float*)d_in[0];
    const float* w_ih      = (const float*)d_in[1];
    const float* w_ih_mask = (const float*)d_in[2];
    const float* w_hh      = (const float*)d_in[3];
    const float* w_hh_mask = (const float*)d_in[4];
    const float* b_ih      = (const float*)d_in[5];
    const float* b_ih_mask = (const float*)d_in[6];
    const float* b_hh      = (const float*)d_in[7];
    const float* b_hh_mask = (const float*)d_in[8];

    float* out = (float*)d_out;
    char*  ws  = (char*)d_ws;
    _Float16* Wih  = (_Float16*)(ws + OFF_WIH);
    _Float16* Whh  = (_Float16*)(ws + OFF_WHH);
    float*    bias = (float*)(ws + OFF_BIAS);
    _Float16* hbuf = (_Float16*)(ws + OFF_HBUF);
    int*      seqf = (int*)(ws + OFF_SEQ);

    prep_kernel<<<dim3(4096), dim3(256), 0, stream>>>(w_ih, w_ih_mask, w_hh, w_hh_mask,
                                                      b_ih, b_ih_mask, b_hh, b_hh_mask,
                                                      Wih, Whh, bias, hbuf, seqf);
    gemm_xproj<<<dim3(2048), dim3(256), 0, stream>>>(seq, Wih, bias, out);
    rnn_steps<<<dim3(32), dim3(256), 0, stream>>>(Whh, out, hbuf, seqf);
}